// Round 2
// baseline (670.497 us; speedup 1.0000x reference)
//
#include <hip/hip_runtime.h>
#include <stdint.h>

#define TPB 512
#define BM 64
#define CTXD 256
#define HID 128
#define TSTEPS 48
#define DTC (1.0f/30.0f)

typedef short short8 __attribute__((ext_vector_type(8)));
typedef float f32x4 __attribute__((ext_vector_type(4)));
typedef float f32x2 __attribute__((ext_vector_type(2)));

// ---------------- LDS layout (bytes) ----------------
#define OFF_WHH 0                 // W_hh bf16 [384] rows, stride 256, XOR swizzle (u&7)<<4
#define OFF_W1  98304             // W1 bf16 [64] rows, stride 256, XOR swizzle
#define OFF_H   114688            // loop: 2 x h bf16 [64 rows][stride 272] (17408 each)
                                  // phase A: ctx bf16 [64 rows][stride 528] (33792)
#define HSTRIDE 272
#define HBUFSZ  17408
#define CSTRIDE 528
#define OFF_PART 149504           // delta partials f32 [4 mt][16 l15][4 jt][2] = 2048 B
#define LDS_BYTES 151552

__device__ __forceinline__ unsigned short f2bf(float f) {
    union { float f; uint32_t u; } v; v.f = f;
    uint32_t r = v.u + 0x7FFFu + ((v.u >> 16) & 1u);
    return (unsigned short)(r >> 16);
}
__device__ __forceinline__ uint32_t pk2bf(float a, float b) {
    return (uint32_t)f2bf(a) | ((uint32_t)f2bf(b) << 16);
}
__device__ __forceinline__ uint32_t pkh2(float a, float b) {
    union { _Float16 h[2]; uint32_t u; } v;
    v.h[0] = (_Float16)a; v.h[1] = (_Float16)b; return v.u;
}
__device__ __forceinline__ float h2lo(uint32_t u) {
    union { uint32_t u; _Float16 h[2]; } v; v.u = u; return (float)v.h[0];
}
__device__ __forceinline__ float h2hi(uint32_t u) {
    union { uint32_t u; _Float16 h[2]; } v; v.u = u; return (float)v.h[1];
}
__device__ __forceinline__ float fsigm(float x) {
    return __builtin_amdgcn_rcpf(1.0f + __expf(-x));
}
__device__ __forceinline__ float ftanhf(float x) {
    return fmaf(-2.0f, __builtin_amdgcn_rcpf(1.0f + __expf(2.0f * x)), 1.0f);
}
__device__ __forceinline__ short8 ldA8(const float* src) {
    f32x2 v0 = *(const f32x2*)(src + 0);
    f32x2 v1 = *(const f32x2*)(src + 2);
    f32x2 v2 = *(const f32x2*)(src + 4);
    f32x2 v3 = *(const f32x2*)(src + 6);
    short8 af;
    af[0] = (short)f2bf(v0.x); af[1] = (short)f2bf(v0.y);
    af[2] = (short)f2bf(v1.x); af[3] = (short)f2bf(v1.y);
    af[4] = (short)f2bf(v2.x); af[5] = (short)f2bf(v2.y);
    af[6] = (short)f2bf(v3.x); af[7] = (short)f2bf(v3.y);
    return af;
}

__global__ __launch_bounds__(TPB, 2)
void dd_kernel(const float* __restrict__ ctx, const float* __restrict__ lv,
               const float* __restrict__ Winit, const float* __restrict__ binit,
               const float* __restrict__ Wih, const float* __restrict__ bih,
               const float* __restrict__ Whh, const float* __restrict__ bhh,
               const float* __restrict__ W1, const float* __restrict__ b1,
               const float* __restrict__ W2, const float* __restrict__ b2,
               float* __restrict__ out)
{
    extern __shared__ char smem[];
    const int tid  = threadIdx.x;
    const int w    = tid >> 6;          // wave 0..7; owns GRU unit tile 16w..16w+15
    const int lane = tid & 63;
    const int g    = (lane >> 4) & 3;
    const int l15  = lane & 15;
    const int row0 = blockIdx.x * BM;
    const int jt   = w & 3;             // MLP tile
    const int mtA  = (w >> 2) * 2;      // MLP row-tile pair base

    // ---------------- stage weights / ctx into LDS ----------------
    for (int p = tid; p < 384 * 64; p += TPB) {           // W_hh bf16, swizzled
        int u = p >> 6, kp = p & 63;
        f32x2 v = *(const f32x2*)(Whh + u * HID + 2 * kp);
        *(uint32_t*)(smem + OFF_WHH + u * 256 + ((4 * kp) ^ ((u & 7) << 4))) = pk2bf(v.x, v.y);
    }
    for (int p = tid; p < 64 * 64; p += TPB) {            // W1 bf16, swizzled
        int u = p >> 6, kp = p & 63;
        f32x2 v = *(const f32x2*)(W1 + u * HID + 2 * kp);
        *(uint32_t*)(smem + OFF_W1 + u * 256 + ((4 * kp) ^ ((u & 7) << 4))) = pk2bf(v.x, v.y);
    }
    for (int p = tid; p < 64 * 128; p += TPB) {           // ctx bf16, padded stride
        int r = p >> 7, kp = p & 127;
        f32x2 v = *(const f32x2*)(ctx + (size_t)(row0 + r) * CTXD + 2 * kp);
        *(uint32_t*)(smem + OFF_H + r * CSTRIDE + 4 * kp) = pk2bf(v.x, v.y);
    }

    // ---------------- per-lane constants (units u = 16w + 4g + r) ----------------
    const int ub = 16 * w + 4 * g;
    float wdr0[4], wdr1[4], wdz0[4], wdz1[4], wdn0[4], wdn1[4], bhnc[4];
    float tbr[4], tbz[4], tbn[4], thi[4], b1c[4], w2c0[4], w2c1[4];
#pragma unroll
    for (int r = 0; r < 4; ++r) {
        int u = ub + r;
        wdr0[r] = Wih[(size_t)u * 258 + 0];         wdr1[r] = Wih[(size_t)u * 258 + 1];
        wdz0[r] = Wih[(size_t)(128 + u) * 258 + 0]; wdz1[r] = Wih[(size_t)(128 + u) * 258 + 1];
        wdn0[r] = Wih[(size_t)(256 + u) * 258 + 0]; wdn1[r] = Wih[(size_t)(256 + u) * 258 + 1];
        bhnc[r] = bhh[256 + u];
        tbr[r]  = bih[u] + bhh[u];
        tbz[r]  = bih[128 + u] + bhh[128 + u];
        tbn[r]  = bih[256 + u];
        thi[r]  = binit[u];
        int um = 16 * jt + 4 * g + r;
        b1c[r]  = b1[um];
        w2c0[r] = W2[um];
        w2c1[r] = W2[64 + um];
    }
    const float b2c0 = b2[0], b2c1 = b2[1];
    float dx[4], dy[4], pos0[4], pos1[4];
#pragma unroll
    for (int mt = 0; mt < 4; ++mt) {
        f32x2 v = *(const f32x2*)(lv + (size_t)(row0 + 16 * mt + l15) * 2);
        dx[mt] = v.x * DTC; dy[mt] = v.y * DTC;
        pos0[mt] = 0.f; pos1[mt] = 0.f;
    }

    __syncthreads();

    // ---------------- Phase A: gi (per-wave gate tile) + h0 ----------------
    // tiles: 0=R(Wih row u), 1=Z(+128), 2=N(+256), 3=h0(Winit)
    f32x4 zero4 = {0.f, 0.f, 0.f, 0.f};
    f32x4 accA[4][4];
#pragma unroll
    for (int jl = 0; jl < 4; ++jl)
#pragma unroll
        for (int mt = 0; mt < 4; ++mt) accA[jl][mt] = zero4;

    const int u16 = 16 * w + l15;
    for (int kk = 0; kk < 8; ++kk) {
        short8 bf[4];
#pragma unroll
        for (int mt = 0; mt < 4; ++mt)
            bf[mt] = *(const short8*)(smem + OFF_H + (16 * mt + l15) * CSTRIDE + 64 * kk + 16 * g);
        short8 afR = ldA8(Wih + (size_t)u16 * 258 + 2 + 32 * kk + 8 * g);
        short8 afZ = ldA8(Wih + (size_t)(128 + u16) * 258 + 2 + 32 * kk + 8 * g);
        short8 afN = ldA8(Wih + (size_t)(256 + u16) * 258 + 2 + 32 * kk + 8 * g);
        short8 afH = ldA8(Winit + (size_t)u16 * 256 + 32 * kk + 8 * g);
#pragma unroll
        for (int mt = 0; mt < 4; ++mt) {
            accA[0][mt] = __builtin_amdgcn_mfma_f32_16x16x32_bf16(afR, bf[mt], accA[0][mt], 0, 0, 0);
            accA[1][mt] = __builtin_amdgcn_mfma_f32_16x16x32_bf16(afZ, bf[mt], accA[1][mt], 0, 0, 0);
            accA[2][mt] = __builtin_amdgcn_mfma_f32_16x16x32_bf16(afN, bf[mt], accA[2][mt], 0, 0, 0);
            accA[3][mt] = __builtin_amdgcn_mfma_f32_16x16x32_bf16(afH, bf[mt], accA[3][mt], 0, 0, 0);
        }
    }

    // pack gi (+biases) as f16 pairs; h0 master copy in f32
    uint32_t gipR[4][2], gipZ[4][2], gipN[4][2];
    float hm[4][4];
#pragma unroll
    for (int mt = 0; mt < 4; ++mt) {
        gipR[mt][0] = pkh2(accA[0][mt][0] + tbr[0], accA[0][mt][1] + tbr[1]);
        gipR[mt][1] = pkh2(accA[0][mt][2] + tbr[2], accA[0][mt][3] + tbr[3]);
        gipZ[mt][0] = pkh2(accA[1][mt][0] + tbz[0], accA[1][mt][1] + tbz[1]);
        gipZ[mt][1] = pkh2(accA[1][mt][2] + tbz[2], accA[1][mt][3] + tbz[3]);
        gipN[mt][0] = pkh2(accA[2][mt][0] + tbn[0], accA[2][mt][1] + tbn[1]);
        gipN[mt][1] = pkh2(accA[2][mt][2] + tbn[2], accA[2][mt][3] + tbn[3]);
#pragma unroll
        for (int r = 0; r < 4; ++r)
            hm[mt][r] = ftanhf(accA[3][mt][r] + thi[r]);
    }
    __syncthreads();              // all ctx reads done; h region reusable

    // write h0 -> buf0 (packed b64)
#pragma unroll
    for (int mt = 0; mt < 4; ++mt) {
        uint2 pk;
        pk.x = pk2bf(hm[mt][0], hm[mt][1]);
        pk.y = pk2bf(hm[mt][2], hm[mt][3]);
        *(uint2*)(smem + OFF_H + (16 * mt + l15) * HSTRIDE + 32 * w + 8 * g) = pk;
    }
    __syncthreads();
    short8 hf[4][4];
#pragma unroll
    for (int mt = 0; mt < 4; ++mt)
#pragma unroll
        for (int kk = 0; kk < 4; ++kk)
            hf[mt][kk] = *(const short8*)(smem + OFF_H + (16 * mt + l15) * HSTRIDE + 64 * kk + 16 * g);

    const int uR = 16 * w + l15;
    const int uZ = 128 + 16 * w + l15;
    const int uN = 256 + 16 * w + l15;
    const int uW = 16 * jt + l15;

    // ---------------- 48-step recurrence ----------------
    for (int t = 0; t < TSTEPS; ++t) {
        const int hoffW = OFF_H + ((t + 1) & 1) * HBUFSZ;   // h_{t+1} buffer
        // GRU preactivations: C-init = gi (R,Z) / bhh_n (N); delta added at gates
        f32x4 aR[4], aZ[4], aN[4];
#pragma unroll
        for (int mt = 0; mt < 4; ++mt) {
            aR[mt][0] = h2lo(gipR[mt][0]); aR[mt][1] = h2hi(gipR[mt][0]);
            aR[mt][2] = h2lo(gipR[mt][1]); aR[mt][3] = h2hi(gipR[mt][1]);
            aZ[mt][0] = h2lo(gipZ[mt][0]); aZ[mt][1] = h2hi(gipZ[mt][0]);
            aZ[mt][2] = h2lo(gipZ[mt][1]); aZ[mt][3] = h2hi(gipZ[mt][1]);
#pragma unroll
            for (int r = 0; r < 4; ++r) aN[mt][r] = bhnc[r];
        }
#pragma unroll
        for (int kk = 0; kk < 4; ++kk) {
            short8 fR = *(const short8*)(smem + OFF_WHH + uR * 256 + ((64 * kk + 16 * g) ^ ((uR & 7) << 4)));
            short8 fZ = *(const short8*)(smem + OFF_WHH + uZ * 256 + ((64 * kk + 16 * g) ^ ((uZ & 7) << 4)));
            short8 fN = *(const short8*)(smem + OFF_WHH + uN * 256 + ((64 * kk + 16 * g) ^ ((uN & 7) << 4)));
#pragma unroll
            for (int mt = 0; mt < 4; ++mt) {
                aR[mt] = __builtin_amdgcn_mfma_f32_16x16x32_bf16(fR, hf[mt][kk], aR[mt], 0, 0, 0);
                aZ[mt] = __builtin_amdgcn_mfma_f32_16x16x32_bf16(fZ, hf[mt][kk], aZ[mt], 0, 0, 0);
                aN[mt] = __builtin_amdgcn_mfma_f32_16x16x32_bf16(fN, hf[mt][kk], aN[mt], 0, 0, 0);
            }
        }
        // gates + h write
#pragma unroll
        for (int mt = 0; mt < 4; ++mt) {
            float ginv[4];
            ginv[0] = h2lo(gipN[mt][0]); ginv[1] = h2hi(gipN[mt][0]);
            ginv[2] = h2lo(gipN[mt][1]); ginv[3] = h2hi(gipN[mt][1]);
#pragma unroll
            for (int r = 0; r < 4; ++r) {
                float rr  = fsigm(aR[mt][r] + dx[mt] * wdr0[r] + dy[mt] * wdr1[r]);
                float zz  = fsigm(aZ[mt][r] + dx[mt] * wdz0[r] + dy[mt] * wdz1[r]);
                float inn = ginv[r] + dx[mt] * wdn0[r] + dy[mt] * wdn1[r];
                float nn  = ftanhf(fmaf(rr, aN[mt][r], inn));
                hm[mt][r] = fmaf(zz, hm[mt][r] - nn, nn);
            }
            uint2 pk;
            pk.x = pk2bf(hm[mt][0], hm[mt][1]);
            pk.y = pk2bf(hm[mt][2], hm[mt][3]);
            *(uint2*)(smem + hoffW + (16 * mt + l15) * HSTRIDE + 32 * w + 8 * g) = pk;
        }
        __syncthreads();          // barrier A: h_{t+1} visible
#pragma unroll
        for (int mt = 0; mt < 4; ++mt)
#pragma unroll
            for (int kk = 0; kk < 4; ++kk)
                hf[mt][kk] = *(const short8*)(smem + hoffW + (16 * mt + l15) * HSTRIDE + 64 * kk + 16 * g);

        // MLP: wave w handles hidden tile jt for row-tiles mtA, mtA+1
        f32x4 a1[2] = {zero4, zero4};
#pragma unroll
        for (int kk = 0; kk < 4; ++kk) {
            short8 wf = *(const short8*)(smem + OFF_W1 + uW * 256 + ((64 * kk + 16 * g) ^ ((uW & 7) << 4)));
            a1[0] = __builtin_amdgcn_mfma_f32_16x16x32_bf16(wf, hf[mtA][kk], a1[0], 0, 0, 0);
            a1[1] = __builtin_amdgcn_mfma_f32_16x16x32_bf16(wf, hf[mtA + 1][kk], a1[1], 0, 0, 0);
        }
        float pv0[2], pv1[2];
#pragma unroll
        for (int p = 0; p < 2; ++p) {
            float s0 = 0.f, s1 = 0.f;
#pragma unroll
            for (int r = 0; r < 4; ++r) {
                float hv = fmaxf(a1[p][r] + b1c[r], 0.f);
                s0 = fmaf(hv, w2c0[r], s0);
                s1 = fmaf(hv, w2c1[r], s1);
            }
            s0 += __shfl_xor(s0, 16, 64); s0 += __shfl_xor(s0, 32, 64);
            s1 += __shfl_xor(s1, 16, 64); s1 += __shfl_xor(s1, 32, 64);
            pv0[p] = s0; pv1[p] = s1;
        }
        if (g < 2) {
            int mtw = mtA + g;
            f32x2 pw;
            pw.x = (g == 0) ? pv0[0] : pv0[1];
            pw.y = (g == 0) ? pv1[0] : pv1[1];
            *(f32x2*)(smem + OFF_PART + mtw * 512 + l15 * 32 + jt * 8) = pw;
        }
        __syncthreads();          // barrier B: partials visible
#pragma unroll
        for (int mt = 0; mt < 4; ++mt) {
            f32x4 q0 = *(const f32x4*)(smem + OFF_PART + mt * 512 + l15 * 32);
            f32x4 q1 = *(const f32x4*)(smem + OFF_PART + mt * 512 + l15 * 32 + 16);
            float pdx = (q0[0] + q0[2]) + (q1[0] + q1[2]) + b2c0;
            float pdy = (q0[1] + q0[3]) + (q1[1] + q1[3]) + b2c1;
            pos0[mt] += pdx; pos1[mt] += pdy;
            dx[mt] = pdx; dy[mt] = pdy;
        }
        if (tid < 16) {
#pragma unroll
            for (int mt = 0; mt < 4; ++mt) {
                f32x2 o2; o2.x = pos0[mt]; o2.y = pos1[mt];
                *(f32x2*)(out + (size_t)(row0 + 16 * mt + l15) * (TSTEPS * 2) + 2 * t) = o2;
            }
        }
    }
}

extern "C" void kernel_launch(void* const* d_in, const int* in_sizes, int n_in,
                              void* d_out, int out_size, void* d_ws, size_t ws_size,
                              hipStream_t stream) {
    (void)in_sizes; (void)n_in; (void)d_ws; (void)ws_size; (void)out_size;
    const float* ctx   = (const float*)d_in[0];
    const float* lv    = (const float*)d_in[1];
    const float* Winit = (const float*)d_in[2];
    const float* binit = (const float*)d_in[3];
    const float* Wih   = (const float*)d_in[4];
    const float* bih   = (const float*)d_in[5];
    const float* Whh   = (const float*)d_in[6];
    const float* bhh   = (const float*)d_in[7];
    const float* W1    = (const float*)d_in[8];
    const float* b1    = (const float*)d_in[9];
    const float* W2    = (const float*)d_in[10];
    const float* b2    = (const float*)d_in[11];
    float* out = (float*)d_out;

    hipFuncSetAttribute(reinterpret_cast<const void*>(dd_kernel),
                        hipFuncAttributeMaxDynamicSharedMemorySize, LDS_BYTES);
    dd_kernel<<<16384 / BM, TPB, LDS_BYTES, stream>>>(
        ctx, lv, Winit, binit, Wih, bih, Whh, bhh, W1, b1, W2, b2, out);
}

// Round 3
// 223.174 us; speedup vs baseline: 3.0044x; 3.0044x over previous
//
#include <hip/hip_runtime.h>
#include <stdint.h>

#define TPB 512
#define BM 64
#define CTXD 256
#define HID 128
#define TSTEPS 48
#define DTC (1.0f/30.0f)

typedef short short8 __attribute__((ext_vector_type(8)));
typedef float f32x4 __attribute__((ext_vector_type(4)));
typedef float f32x2 __attribute__((ext_vector_type(2)));

// ---------------- LDS layout (bytes) ----------------
#define OFF_WHH 0                 // W_hh bf16 [384] rows, stride 256, XOR swizzle (u&7)<<4
#define OFF_W1  98304             // W1 bf16 [64] rows, stride 256, XOR swizzle
#define OFF_H   114688            // loop: 2 x h bf16 [64 rows][stride 272] (17408 each)
                                  // phase A: ctx bf16 [64 rows][stride 528] (33792)
#define HSTRIDE 272
#define HBUFSZ  17408
#define CSTRIDE 528
#define OFF_PART 149504           // delta partials f32 [4 mt][16 l15][4 jt][2] = 2048 B
#define LDS_BYTES 151552

__device__ __forceinline__ unsigned short f2bf(float f) {
    union { float f; uint32_t u; } v; v.f = f;
    uint32_t r = v.u + 0x7FFFu + ((v.u >> 16) & 1u);
    return (unsigned short)(r >> 16);
}
__device__ __forceinline__ uint32_t pk2bf(float a, float b) {
    return (uint32_t)f2bf(a) | ((uint32_t)f2bf(b) << 16);
}
__device__ __forceinline__ uint32_t pkh2(float a, float b) {
    union { _Float16 h[2]; uint32_t u; } v;
    v.h[0] = (_Float16)a; v.h[1] = (_Float16)b; return v.u;
}
__device__ __forceinline__ float h2lo(uint32_t u) {
    union { uint32_t u; _Float16 h[2]; } v; v.u = u; return (float)v.h[0];
}
__device__ __forceinline__ float h2hi(uint32_t u) {
    union { uint32_t u; _Float16 h[2]; } v; v.u = u; return (float)v.h[1];
}
__device__ __forceinline__ float fsigm(float x) {
    return __builtin_amdgcn_rcpf(1.0f + __expf(-x));
}
__device__ __forceinline__ float ftanhf(float x) {
    return fmaf(-2.0f, __builtin_amdgcn_rcpf(1.0f + __expf(2.0f * x)), 1.0f);
}
__device__ __forceinline__ short8 ldA8(const float* src) {
    f32x2 v0 = *(const f32x2*)(src + 0);
    f32x2 v1 = *(const f32x2*)(src + 2);
    f32x2 v2 = *(const f32x2*)(src + 4);
    f32x2 v3 = *(const f32x2*)(src + 6);
    short8 af;
    af[0] = (short)f2bf(v0.x); af[1] = (short)f2bf(v0.y);
    af[2] = (short)f2bf(v1.x); af[3] = (short)f2bf(v1.y);
    af[4] = (short)f2bf(v2.x); af[5] = (short)f2bf(v2.y);
    af[6] = (short)f2bf(v3.x); af[7] = (short)f2bf(v3.y);
    return af;
}

__global__ __launch_bounds__(TPB, 2)
void dd_kernel(const float* __restrict__ ctx, const float* __restrict__ lv,
               const float* __restrict__ Winit, const float* __restrict__ binit,
               const float* __restrict__ Wih, const float* __restrict__ bih,
               const float* __restrict__ Whh, const float* __restrict__ bhh,
               const float* __restrict__ W1, const float* __restrict__ b1,
               const float* __restrict__ W2, const float* __restrict__ b2,
               float* __restrict__ out)
{
    extern __shared__ char smem[];
    const int tid  = threadIdx.x;
    const int w    = tid >> 6;          // wave 0..7; owns GRU unit tile 16w..16w+15
    const int lane = tid & 63;
    const int g    = (lane >> 4) & 3;
    const int l15  = lane & 15;
    const int row0 = blockIdx.x * BM;
    const int jt   = w & 3;             // MLP hidden tile
    const int mtA  = (w >> 2) * 2;      // MLP row-tile pair base (0 or 2) — runtime, LDS-addr only!

    // ---------------- stage weights / ctx into LDS ----------------
    for (int p = tid; p < 384 * 64; p += TPB) {           // W_hh bf16, swizzled
        int u = p >> 6, kp = p & 63;
        f32x2 v = *(const f32x2*)(Whh + u * HID + 2 * kp);
        *(uint32_t*)(smem + OFF_WHH + u * 256 + ((4 * kp) ^ ((u & 7) << 4))) = pk2bf(v.x, v.y);
    }
    for (int p = tid; p < 64 * 64; p += TPB) {            // W1 bf16, swizzled
        int u = p >> 6, kp = p & 63;
        f32x2 v = *(const f32x2*)(W1 + u * HID + 2 * kp);
        *(uint32_t*)(smem + OFF_W1 + u * 256 + ((4 * kp) ^ ((u & 7) << 4))) = pk2bf(v.x, v.y);
    }
    for (int p = tid; p < 64 * 128; p += TPB) {           // ctx bf16, padded stride
        int r = p >> 7, kp = p & 127;
        f32x2 v = *(const f32x2*)(ctx + (size_t)(row0 + r) * CTXD + 2 * kp);
        *(uint32_t*)(smem + OFF_H + r * CSTRIDE + 4 * kp) = pk2bf(v.x, v.y);
    }

    // ---------------- per-lane constants (units u = 16w + 4g + r) ----------------
    const int ub = 16 * w + 4 * g;
    float wdr0[4], wdr1[4], wdz0[4], wdz1[4], wdn0[4], wdn1[4], bhnc[4];
    float tbr[4], tbz[4], tbn[4], thi[4], b1c[4], w2c0[4], w2c1[4];
#pragma unroll
    for (int r = 0; r < 4; ++r) {
        int u = ub + r;
        wdr0[r] = Wih[(size_t)u * 258 + 0];         wdr1[r] = Wih[(size_t)u * 258 + 1];
        wdz0[r] = Wih[(size_t)(128 + u) * 258 + 0]; wdz1[r] = Wih[(size_t)(128 + u) * 258 + 1];
        wdn0[r] = Wih[(size_t)(256 + u) * 258 + 0]; wdn1[r] = Wih[(size_t)(256 + u) * 258 + 1];
        bhnc[r] = bhh[256 + u];
        tbr[r]  = bih[u] + bhh[u];
        tbz[r]  = bih[128 + u] + bhh[128 + u];
        tbn[r]  = bih[256 + u];
        thi[r]  = binit[u];
        int um = 16 * jt + 4 * g + r;
        b1c[r]  = b1[um];
        w2c0[r] = W2[um];
        w2c1[r] = W2[64 + um];
    }
    const float b2c0 = b2[0], b2c1 = b2[1];
    float dx[4], dy[4], pos0[4], pos1[4];
#pragma unroll
    for (int mt = 0; mt < 4; ++mt) {
        f32x2 v = *(const f32x2*)(lv + (size_t)(row0 + 16 * mt + l15) * 2);
        dx[mt] = v.x * DTC; dy[mt] = v.y * DTC;
        pos0[mt] = 0.f; pos1[mt] = 0.f;
    }

    __syncthreads();

    // ---------------- Phase A: gi (per-wave gate tile) + h0 ----------------
    f32x4 zero4 = {0.f, 0.f, 0.f, 0.f};
    f32x4 accA[4][4];
#pragma unroll
    for (int jl = 0; jl < 4; ++jl)
#pragma unroll
        for (int mt = 0; mt < 4; ++mt) accA[jl][mt] = zero4;

    const int u16 = 16 * w + l15;
    for (int kk = 0; kk < 8; ++kk) {
        short8 bf[4];
#pragma unroll
        for (int mt = 0; mt < 4; ++mt)
            bf[mt] = *(const short8*)(smem + OFF_H + (16 * mt + l15) * CSTRIDE + 64 * kk + 16 * g);
        short8 afR = ldA8(Wih + (size_t)u16 * 258 + 2 + 32 * kk + 8 * g);
        short8 afZ = ldA8(Wih + (size_t)(128 + u16) * 258 + 2 + 32 * kk + 8 * g);
        short8 afN = ldA8(Wih + (size_t)(256 + u16) * 258 + 2 + 32 * kk + 8 * g);
        short8 afH = ldA8(Winit + (size_t)u16 * 256 + 32 * kk + 8 * g);
#pragma unroll
        for (int mt = 0; mt < 4; ++mt) {
            accA[0][mt] = __builtin_amdgcn_mfma_f32_16x16x32_bf16(afR, bf[mt], accA[0][mt], 0, 0, 0);
            accA[1][mt] = __builtin_amdgcn_mfma_f32_16x16x32_bf16(afZ, bf[mt], accA[1][mt], 0, 0, 0);
            accA[2][mt] = __builtin_amdgcn_mfma_f32_16x16x32_bf16(afN, bf[mt], accA[2][mt], 0, 0, 0);
            accA[3][mt] = __builtin_amdgcn_mfma_f32_16x16x32_bf16(afH, bf[mt], accA[3][mt], 0, 0, 0);
        }
    }

    // pack gi (+biases) as f16 pairs; h0 master copy in f32
    uint32_t gipR[4][2], gipZ[4][2], gipN[4][2];
    float hm[4][4];
#pragma unroll
    for (int mt = 0; mt < 4; ++mt) {
        gipR[mt][0] = pkh2(accA[0][mt][0] + tbr[0], accA[0][mt][1] + tbr[1]);
        gipR[mt][1] = pkh2(accA[0][mt][2] + tbr[2], accA[0][mt][3] + tbr[3]);
        gipZ[mt][0] = pkh2(accA[1][mt][0] + tbz[0], accA[1][mt][1] + tbz[1]);
        gipZ[mt][1] = pkh2(accA[1][mt][2] + tbz[2], accA[1][mt][3] + tbz[3]);
        gipN[mt][0] = pkh2(accA[2][mt][0] + tbn[0], accA[2][mt][1] + tbn[1]);
        gipN[mt][1] = pkh2(accA[2][mt][2] + tbn[2], accA[2][mt][3] + tbn[3]);
#pragma unroll
        for (int r = 0; r < 4; ++r)
            hm[mt][r] = ftanhf(accA[3][mt][r] + thi[r]);
    }
    __syncthreads();              // all ctx reads done; h region reusable

    // write h0 -> buf0 (packed b64)
#pragma unroll
    for (int mt = 0; mt < 4; ++mt) {
        uint2 pk;
        pk.x = pk2bf(hm[mt][0], hm[mt][1]);
        pk.y = pk2bf(hm[mt][2], hm[mt][3]);
        *(uint2*)(smem + OFF_H + (16 * mt + l15) * HSTRIDE + 32 * w + 8 * g) = pk;
    }
    __syncthreads();
    short8 hf[4][4];              // ONLY compile-time indices touch this array (rule #20)
#pragma unroll
    for (int mt = 0; mt < 4; ++mt)
#pragma unroll
        for (int kk = 0; kk < 4; ++kk)
            hf[mt][kk] = *(const short8*)(smem + OFF_H + (16 * mt + l15) * HSTRIDE + 64 * kk + 16 * g);

    const int uR = 16 * w + l15;
    const int uZ = 128 + 16 * w + l15;
    const int uN = 256 + 16 * w + l15;
    const int uW = 16 * jt + l15;

    // ---------------- 48-step recurrence ----------------
    for (int t = 0; t < TSTEPS; ++t) {
        const int hoffW = OFF_H + ((t + 1) & 1) * HBUFSZ;   // h_{t+1} buffer
        f32x4 aR[4], aZ[4], aN[4];
#pragma unroll
        for (int mt = 0; mt < 4; ++mt) {
            aR[mt][0] = h2lo(gipR[mt][0]); aR[mt][1] = h2hi(gipR[mt][0]);
            aR[mt][2] = h2lo(gipR[mt][1]); aR[mt][3] = h2hi(gipR[mt][1]);
            aZ[mt][0] = h2lo(gipZ[mt][0]); aZ[mt][1] = h2hi(gipZ[mt][0]);
            aZ[mt][2] = h2lo(gipZ[mt][1]); aZ[mt][3] = h2hi(gipZ[mt][1]);
#pragma unroll
            for (int r = 0; r < 4; ++r) aN[mt][r] = bhnc[r];
        }
#pragma unroll
        for (int kk = 0; kk < 4; ++kk) {
            short8 fR = *(const short8*)(smem + OFF_WHH + uR * 256 + ((64 * kk + 16 * g) ^ ((uR & 7) << 4)));
            short8 fZ = *(const short8*)(smem + OFF_WHH + uZ * 256 + ((64 * kk + 16 * g) ^ ((uZ & 7) << 4)));
            short8 fN = *(const short8*)(smem + OFF_WHH + uN * 256 + ((64 * kk + 16 * g) ^ ((uN & 7) << 4)));
#pragma unroll
            for (int mt = 0; mt < 4; ++mt) {
                aR[mt] = __builtin_amdgcn_mfma_f32_16x16x32_bf16(fR, hf[mt][kk], aR[mt], 0, 0, 0);
                aZ[mt] = __builtin_amdgcn_mfma_f32_16x16x32_bf16(fZ, hf[mt][kk], aZ[mt], 0, 0, 0);
                aN[mt] = __builtin_amdgcn_mfma_f32_16x16x32_bf16(fN, hf[mt][kk], aN[mt], 0, 0, 0);
            }
        }
        // gates + h write
#pragma unroll
        for (int mt = 0; mt < 4; ++mt) {
            float ginv[4];
            ginv[0] = h2lo(gipN[mt][0]); ginv[1] = h2hi(gipN[mt][0]);
            ginv[2] = h2lo(gipN[mt][1]); ginv[3] = h2hi(gipN[mt][1]);
#pragma unroll
            for (int r = 0; r < 4; ++r) {
                float rr  = fsigm(aR[mt][r] + dx[mt] * wdr0[r] + dy[mt] * wdr1[r]);
                float zz  = fsigm(aZ[mt][r] + dx[mt] * wdz0[r] + dy[mt] * wdz1[r]);
                float inn = ginv[r] + dx[mt] * wdn0[r] + dy[mt] * wdn1[r];
                float nn  = ftanhf(fmaf(rr, aN[mt][r], inn));
                hm[mt][r] = fmaf(zz, hm[mt][r] - nn, nn);
            }
            uint2 pk;
            pk.x = pk2bf(hm[mt][0], hm[mt][1]);
            pk.y = pk2bf(hm[mt][2], hm[mt][3]);
            *(uint2*)(smem + hoffW + (16 * mt + l15) * HSTRIDE + 32 * w + 8 * g) = pk;
        }
        __syncthreads();          // barrier A: h_{t+1} visible
#pragma unroll
        for (int mt = 0; mt < 4; ++mt)
#pragma unroll
            for (int kk = 0; kk < 4; ++kk)
                hf[mt][kk] = *(const short8*)(smem + hoffW + (16 * mt + l15) * HSTRIDE + 64 * kk + 16 * g);

        // MLP: wave w handles hidden tile jt for row-tiles mtA, mtA+1.
        // Read B-operands straight from LDS with the runtime row base (NOT hf[mtA][..]
        // — runtime-indexing the register array sent it to scratch in round 2).
        f32x4 a1[2] = {zero4, zero4};
#pragma unroll
        for (int kk = 0; kk < 4; ++kk) {
            short8 wf = *(const short8*)(smem + OFF_W1 + uW * 256 + ((64 * kk + 16 * g) ^ ((uW & 7) << 4)));
            short8 hA = *(const short8*)(smem + hoffW + (16 * mtA + l15) * HSTRIDE + 64 * kk + 16 * g);
            short8 hB = *(const short8*)(smem + hoffW + (16 * mtA + 16 + l15) * HSTRIDE + 64 * kk + 16 * g);
            a1[0] = __builtin_amdgcn_mfma_f32_16x16x32_bf16(wf, hA, a1[0], 0, 0, 0);
            a1[1] = __builtin_amdgcn_mfma_f32_16x16x32_bf16(wf, hB, a1[1], 0, 0, 0);
        }
        float pv0[2], pv1[2];
#pragma unroll
        for (int p = 0; p < 2; ++p) {
            float s0 = 0.f, s1 = 0.f;
#pragma unroll
            for (int r = 0; r < 4; ++r) {
                float hv = fmaxf(a1[p][r] + b1c[r], 0.f);
                s0 = fmaf(hv, w2c0[r], s0);
                s1 = fmaf(hv, w2c1[r], s1);
            }
            s0 += __shfl_xor(s0, 16, 64); s0 += __shfl_xor(s0, 32, 64);
            s1 += __shfl_xor(s1, 16, 64); s1 += __shfl_xor(s1, 32, 64);
            pv0[p] = s0; pv1[p] = s1;
        }
        if (g < 2) {
            int mtw = mtA + g;
            f32x2 pw;
            pw.x = (g == 0) ? pv0[0] : pv0[1];
            pw.y = (g == 0) ? pv1[0] : pv1[1];
            *(f32x2*)(smem + OFF_PART + mtw * 512 + l15 * 32 + jt * 8) = pw;
        }
        __syncthreads();          // barrier B: partials visible
#pragma unroll
        for (int mt = 0; mt < 4; ++mt) {
            f32x4 q0 = *(const f32x4*)(smem + OFF_PART + mt * 512 + l15 * 32);
            f32x4 q1 = *(const f32x4*)(smem + OFF_PART + mt * 512 + l15 * 32 + 16);
            float pdx = (q0[0] + q0[2]) + (q1[0] + q1[2]) + b2c0;
            float pdy = (q0[1] + q0[3]) + (q1[1] + q1[3]) + b2c1;
            pos0[mt] += pdx; pos1[mt] += pdy;
            dx[mt] = pdx; dy[mt] = pdy;
        }
        if (tid < 16) {
#pragma unroll
            for (int mt = 0; mt < 4; ++mt) {
                f32x2 o2; o2.x = pos0[mt]; o2.y = pos1[mt];
                *(f32x2*)(out + (size_t)(row0 + 16 * mt + l15) * (TSTEPS * 2) + 2 * t) = o2;
            }
        }
    }
}

extern "C" void kernel_launch(void* const* d_in, const int* in_sizes, int n_in,
                              void* d_out, int out_size, void* d_ws, size_t ws_size,
                              hipStream_t stream) {
    (void)in_sizes; (void)n_in; (void)d_ws; (void)ws_size; (void)out_size;
    const float* ctx   = (const float*)d_in[0];
    const float* lv    = (const float*)d_in[1];
    const float* Winit = (const float*)d_in[2];
    const float* binit = (const float*)d_in[3];
    const float* Wih   = (const float*)d_in[4];
    const float* bih   = (const float*)d_in[5];
    const float* Whh   = (const float*)d_in[6];
    const float* bhh   = (const float*)d_in[7];
    const float* W1    = (const float*)d_in[8];
    const float* b1    = (const float*)d_in[9];
    const float* W2    = (const float*)d_in[10];
    const float* b2    = (const float*)d_in[11];
    float* out = (float*)d_out;

    hipFuncSetAttribute(reinterpret_cast<const void*>(dd_kernel),
                        hipFuncAttributeMaxDynamicSharedMemorySize, LDS_BYTES);
    dd_kernel<<<16384 / BM, TPB, LDS_BYTES, stream>>>(
        ctx, lv, Winit, binit, Wih, bih, Whh, bhh, W1, b1, W2, b2, out);
}